// Round 6
// baseline (721.335 us; speedup 1.0000x reference)
//
#include <hip/hip_runtime.h>

#define T 32
#define B 256

typedef int v4i __attribute__((ext_vector_type(4)));

// ---------------- workspace byte offsets ----------------
#define OFF_BD2   0            // int8 [5][128][576]   conv2 digits      368,640
#define OFF_BD3   368640       // int8 [5][256][1152]  conv3 digits    1,474,560
#define OFF_BDTC  1843200      // int8 [5][256][768]   tc digits         983,040
#define OFF_BDF1  2826240      // int8 [5][128][256]   fc1 digits        163,840
#define OFF_RECWT 2990080      // double [256][256]                      524,288
#define OFF_S1    3514368      // uchar [T][B][pix64][ic64]           33,554,432
#define OFF_POOL  37068800     // uchar [w9][t32][b256][oc128]         9,437,184
#define OFF_PSP3  46505984     // double [8192][256]                  16,777,216
#define OFF_S3    63283200     // uchar [t][b][256]                    2,097,152
#define OFF_PSPTC 65380352     // double [8192][256]                  16,777,216
#define OFF_TC    82157568     // uchar [t][b][256]                    2,097,152
#define OFF_R     84254720     // uchar [t][b][256]                    2,097,152
#define OFF_PSPF1 OFF_PSPTC    // double [8192][128] — reuses psptc (retired)
// total 86,351,872 bytes

// ---------------- rec weight transpose (fp64) ----------------
__global__ __launch_bounds__(256) void k_prep(const float* __restrict__ rcw,
        double* __restrict__ recwt) {
    int n = blockIdx.x * 256 + threadIdx.x;        // k*256+oc
    int oc = n & 255, k = n >> 8;
    recwt[n] = (double)rcw[oc * 256 + k];
}

// ---------------- weight digit decomposition (all i8-GEMM layers) ----------------
// W = rint(w*2^38), 5 signed base-256 digits; layouts: Bd[d][oc][k]
__global__ __launch_bounds__(256) void k_prepd(const float* __restrict__ c2w,
        const float* __restrict__ c3w, const float* __restrict__ tcw,
        const float* __restrict__ f1w, signed char* __restrict__ Bd2,
        signed char* __restrict__ Bd3, signed char* __restrict__ Bdtc,
        signed char* __restrict__ Bdf1) {
    int idx = blockIdx.x * 256 + threadIdx.x;
    float w; signed char* base; int plane, off;
    if (idx < 73728) {                       // conv2: k=(ky*3+kx)*64+ic
        int oc = idx / 576, kpos = idx - oc * 576;
        int kk = kpos >> 6, ic = kpos & 63;
        int ky = kk / 3, kx = kk - ky * 3;
        w = c2w[((oc * 64 + ic) * 3 + ky) * 3 + kx];
        base = Bd2; plane = 73728; off = idx;
    } else if (idx < 368640) {               // conv3: k = win*128+ic
        int m = idx - 73728;
        int oc = m / 1152, kpos = m - oc * 1152;
        int win = kpos >> 7, ic = kpos & 127;
        w = c3w[(oc * 128 + ic) * 9 + win];
        base = Bd3; plane = 294912; off = m;
    } else if (idx < 565248) {               // tc: k = j*256+kc (j = oldest-first tap)
        int m = idx - 368640;
        int oc = m / 768, kpos = m - oc * 768;
        int j = kpos >> 8, kc = kpos & 255;
        w = tcw[(j * 256 + oc) * 256 + kc];
        base = Bdtc; plane = 196608; off = m;
    } else if (idx < 598016) {               // fc1: k = kc
        int m = idx - 565248;
        int oc = m >> 8, kc = m & 255;
        w = f1w[oc * 256 + kc];
        base = Bdf1; plane = 32768; off = m;
    } else return;
    long long W = (long long)rint((double)w * 274877906944.0);   // 2^38
#pragma unroll
    for (int d = 0; d < 4; ++d) {
        int dig = (int)(((W + 128) & 255) - 128);
        base[d * plane + off] = (signed char)dig;
        W = (W - dig) >> 8;
    }
    base[4 * plane + off] = (signed char)W;
}

// ---------------- bias pre-fill for atomic-accumulated psp tensors --------------
__global__ __launch_bounds__(256) void k_fill3(const float* __restrict__ b3,
        double* __restrict__ psp) {
    int i = blockIdx.x * 256 + threadIdx.x;        // 8192*256
    psp[i] = (double)b3[i & 255];
}
__global__ __launch_bounds__(256) void k_filltc(const float* __restrict__ tcb,
        double* __restrict__ psp) {
    int i = blockIdx.x * 256 + threadIdx.x;
    int c = i & 255, t = i >> 16;                  // row = i>>8, t = row>>8
    double bias = (double)tcb[c];
    if (t >= 1) bias += (double)tcb[256 + c];
    if (t >= 2) bias += (double)tcb[512 + c];
    psp[i] = bias;
}

// ---------------- conv1 + LIF1 -> s1 [t][b][pix][ic], fp64 state ----------------
__global__ __launch_bounds__(256) void k_conv1(const float* __restrict__ x,
        const float* __restrict__ w1, const float* __restrict__ b1,
        unsigned char* __restrict__ s1) {
    __shared__ float xl[3200];
    int b  = blockIdx.x;
    int oc = threadIdx.x & 63;
    int pg = threadIdx.x >> 6;              // 0..3
    const float* xb = x + b * 3200;         // input_data[b][0][10][10][T], t innermost
    for (int i = threadIdx.x; i < 3200; i += 256)
        xl[(i & 31) * 100 + (i >> 5)] = xb[i];   // LDS [t][pos]
    double wd[9];
#pragma unroll
    for (int j = 0; j < 9; ++j) wd[j] = (double)w1[oc * 9 + j];
    double bias = (double)b1[oc];
    __syncthreads();
    double cur[16], vlt[16];
    unsigned spkb = 0;
#pragma unroll
    for (int i = 0; i < 16; ++i) { cur[i] = 0.0; vlt[i] = 0.0; }
    for (int t = 0; t < T; ++t) {
#pragma unroll
        for (int i = 0; i < 16; ++i) {
            int pix = pg * 16 + i;
            int oy = pix >> 3, ox = pix & 7;
            const float* xt = &xl[t * 100 + oy * 10 + ox];
            double z = bias;
#pragma unroll
            for (int ky = 0; ky < 3; ++ky)
#pragma unroll
                for (int kx = 0; kx < 3; ++kx)
                    z = fma(wd[ky * 3 + kx], (double)xt[ky * 10 + kx], z);
            cur[i] = 0.5 * cur[i] + z;
            int s = (spkb >> i) & 1;
            vlt[i] = (s ? 0.0 : 0.75 * vlt[i]) + cur[i];
            s = (vlt[i] > 0.5) ? 1 : 0;
            spkb = (spkb & ~(1u << i)) | ((unsigned)s << i);
            s1[((size_t)(t * B + b) * 64 + pix) * 64 + oc] = (unsigned char)s;
        }
    }
}

// ---------------- conv2: B-in-registers i8-digit MFMA + LIF + avgpool -----------
// grid B*9 ; block 256 (4 waves). Per (wave,nh): all 45 B-fragments cached in
// VGPRs, reused across the 4 mp tiles -> zero global loads in the K-loop.
// A in LDS with XOR bank swizzle: unit f = q*16 + (p ^ 2*(t&3)), t-stride 1024.
__global__ __launch_bounds__(256) void k_conv2(const unsigned char* __restrict__ s1,
        const signed char* __restrict__ Bd2, const float* __restrict__ cb2,
        unsigned char* __restrict__ pooled) {
    __shared__ __align__(16) unsigned char As[32 * 1024];
    __shared__ double pl[2][4][4][64];
    __shared__ unsigned smask[4][64];
    const int b = blockIdx.x / 9;
    const int w = blockIdx.x - b * 9;
    const int wy = w / 3, wx = w - wy * 3;
    const int tid = threadIdx.x;
    const int wave = tid >> 6, lane = tid & 63;
    const int col = lane & 15, quad = lane >> 4;
    const int m = lane & 15;
    const int tq = m >> 2, apx = m & 3;
    const int apy = apx >> 1, apxx = apx & 1;
    const int oc_l = tid & 63, px_e = tid >> 6;
    const double scl[5] = { 0x1p-38, 0x1p-30, 0x1p-22, 0x1p-14, 0x1p-6 };

    {   // stage A (swizzled)
        const int pixbase = (2 * wy) * 8 + 2 * wx;
        for (int c = tid; c < 2048; c += 256) {
            int t = c >> 6, rem = c & 63;
            int p = rem >> 2, qo = rem & 3;
            int ly = p >> 2, lx = p & 3;
            int pix = pixbase + ly * 8 + lx;
            v4i v = *(const v4i*)(s1 + (((size_t)(t * B + b) * 64 + pix) << 6) + qo * 16);
            *(v4i*)(As + t * 1024 + (qo * 16 + (p ^ (2 * (t & 3)))) * 16) = v;
        }
    }
    __syncthreads();

    for (int nh = 0; nh < 2; ++nh) {
        const signed char* Bw = Bd2 + (size_t)(nh * 64 + wave * 16 + col) * 576 + quad * 16;
        v4i Bc[45];
#pragma unroll
        for (int kk = 0; kk < 9; ++kk)
#pragma unroll
            for (int d = 0; d < 5; ++d)
                Bc[kk * 5 + d] = *(const v4i*)(Bw + d * 73728 + kk * 64);

        double cur = 0.0, vlt = 0.0;
        int spk = 0;
        unsigned bits = 0;
        double bias = (double)cb2[nh * 64 + oc_l];

        for (int mp = 0; mp < 4; ++mp) {
            v4i acc[5];
            // ---- j = 0 (t = mp*8 + tq) ----
#pragma unroll
            for (int d = 0; d < 5; ++d) acc[d] = (v4i){0, 0, 0, 0};
#pragma unroll
            for (int ky = 0; ky < 3; ++ky)
#pragma unroll
                for (int kx = 0; kx < 3; ++kx) {
                    const int kk = ky * 3 + kx;
                    const int p = (apy + ky) * 4 + (apxx + kx);
                    v4i Af = *(const v4i*)(As + (mp * 8 + tq) * 1024
                                           + (quad * 16 + (p ^ (2 * tq))) * 16);
#pragma unroll
                    for (int d = 0; d < 5; ++d)
                        acc[d] = __builtin_amdgcn_mfma_i32_16x16x64_i8(Af, Bc[kk * 5 + d], acc[d], 0, 0, 0);
                }
            __syncthreads();                 // previous mp's pl consumers done
#pragma unroll
            for (int r = 0; r < 4; ++r) {
                double p = 0.0;
#pragma unroll
                for (int d = 0; d < 5; ++d) p = fma((double)acc[d][r], scl[d], p);
                pl[0][quad][r][wave * 16 + col] = p;
            }
            // ---- j = 1 (t = mp*8 + 4 + tq) ----
#pragma unroll
            for (int d = 0; d < 5; ++d) acc[d] = (v4i){0, 0, 0, 0};
#pragma unroll
            for (int ky = 0; ky < 3; ++ky)
#pragma unroll
                for (int kx = 0; kx < 3; ++kx) {
                    const int kk = ky * 3 + kx;
                    const int p = (apy + ky) * 4 + (apxx + kx);
                    v4i Af = *(const v4i*)(As + (mp * 8 + 4 + tq) * 1024
                                           + (quad * 16 + (p ^ (2 * tq))) * 16);
#pragma unroll
                    for (int d = 0; d < 5; ++d)
                        acc[d] = __builtin_amdgcn_mfma_i32_16x16x64_i8(Af, Bc[kk * 5 + d], acc[d], 0, 0, 0);
                }
#pragma unroll
            for (int r = 0; r < 4; ++r) {
                double p = 0.0;
#pragma unroll
                for (int d = 0; d < 5; ++d) p = fma((double)acc[d][r], scl[d], p);
                pl[1][quad][r][wave * 16 + col] = p;
            }
            __syncthreads();
            // LIF advance: 8 timesteps, thread owns neuron (oc_l, px_e)
#pragma unroll
            for (int j = 0; j < 2; ++j)
#pragma unroll
                for (int q = 0; q < 4; ++q) {
                    int t = (2 * mp + j) * 4 + q;
                    double z = bias + pl[j][q][px_e][oc_l];
                    cur = 0.5 * cur + z;
                    vlt = (spk ? 0.0 : 0.75 * vlt) + cur;
                    spk = (vlt > 0.5) ? 1 : 0;
                    bits |= ((unsigned)spk) << t;
                }
        }
        smask[px_e][oc_l] = bits;
        __syncthreads();
        {
            int tt = tid >> 6;               // 0..3
#pragma unroll
            for (int q = 0; q < 8; ++q) {
                int t = q * 4 + tt;
                unsigned s = ((smask[0][oc_l] >> t) & 1) + ((smask[1][oc_l] >> t) & 1)
                           + ((smask[2][oc_l] >> t) & 1) + ((smask[3][oc_l] >> t) & 1);
                pooled[(size_t)((w * 32 + t) * 256 + b) * 128 + nh * 64 + oc_l] = (unsigned char)s;
            }
        }
        __syncthreads();
    }
}

// ---------------- conv3 PSP: digit-split i8 GEMM, exact fp64 atomic combine -----
// grid 1280 = 5 d x 256 M-blocks (M=32) ; block 256 (4 waves x N64)
__global__ __launch_bounds__(256) void k_c3psp(const unsigned char* __restrict__ pooled,
        const signed char* __restrict__ Bd3, double* __restrict__ psp) {
    __shared__ __align__(16) unsigned char As[32 * 1168];
    const int d = blockIdx.x >> 8;
    const int rbase = (blockIdx.x & 255) * 32;
    const int tid = threadIdx.x;
    const int wave = tid >> 6, lane = tid & 63;
    const int col = lane & 15, quad = lane >> 4;
    for (int c = tid; c < 2304; c += 256) {       // 32 rows x 72 chunks
        int row = c / 72, cho = c - row * 72;
        int wn = cho >> 3, ico = (cho & 7) * 16;
        v4i v = *(const v4i*)(pooled + ((size_t)(wn * 8192) + rbase + row) * 128 + ico);
        *(v4i*)(As + row * 1168 + cho * 16) = v;
    }
    __syncthreads();
    const int nb = wave * 64;
    const double scl[5] = { 0x1p-40, 0x1p-32, 0x1p-24, 0x1p-16, 0x1p-8 };  // folds /4 pool
    const double s = scl[d];
    const signed char* Bp = Bd3 + (size_t)d * 294912 + (size_t)(nb + col) * 1152 + quad * 16;
    v4i acc[4][2];
#pragma unroll
    for (int nt = 0; nt < 4; ++nt) { acc[nt][0] = (v4i){0,0,0,0}; acc[nt][1] = (v4i){0,0,0,0}; }
    v4i Bc[4], Bn[4];
#pragma unroll
    for (int nt = 0; nt < 4; ++nt) Bc[nt] = *(const v4i*)(Bp + nt * 18432);
#pragma unroll
    for (int kk = 0; kk < 18; ++kk) {
        if (kk < 17) {
#pragma unroll
            for (int nt = 0; nt < 4; ++nt)
                Bn[nt] = *(const v4i*)(Bp + nt * 18432 + (kk + 1) * 64);
        }
        v4i Af0 = *(const v4i*)(As + (lane & 15) * 1168 + kk * 64 + quad * 16);
        v4i Af1 = *(const v4i*)(As + ((lane & 15) + 16) * 1168 + kk * 64 + quad * 16);
#pragma unroll
        for (int nt = 0; nt < 4; ++nt) {
            acc[nt][0] = __builtin_amdgcn_mfma_i32_16x16x64_i8(Af0, Bc[nt], acc[nt][0], 0, 0, 0);
            acc[nt][1] = __builtin_amdgcn_mfma_i32_16x16x64_i8(Af1, Bc[nt], acc[nt][1], 0, 0, 0);
        }
#pragma unroll
        for (int nt = 0; nt < 4; ++nt) Bc[nt] = Bn[nt];
    }
#pragma unroll
    for (int nt = 0; nt < 4; ++nt)
#pragma unroll
        for (int mi = 0; mi < 2; ++mi)
#pragma unroll
            for (int r = 0; r < 4; ++r) {
                int row = rbase + mi * 16 + quad * 4 + r;
                // exact: int * pow2, total digit span < 53 bits -> order-free
                atomicAdd(&psp[(size_t)row * 256 + nb + nt * 16 + col],
                          (double)acc[nt][mi][r] * s);
            }
}

// ---------------- tc PSP: digit-split i8 GEMM (3-tap history), atomic combine ---
// grid 1280 = 5 d x 256 M-blocks (M=32, single t per block) ; block 256
__global__ __launch_bounds__(256) void k_tcpsp(const unsigned char* __restrict__ s3,
        const signed char* __restrict__ Bdtc, double* __restrict__ psp) {
    __shared__ __align__(16) unsigned char As[32 * 784];
    const int d = blockIdx.x >> 8;
    const int rbase = (blockIdx.x & 255) * 32;
    const int t = rbase >> 8;
    const int tid = threadIdx.x;
    const int wave = tid >> 6, lane = tid & 63;
    const int col = lane & 15, quad = lane >> 4;
    for (int c = tid; c < 1536; c += 256) {        // 32 rows x 48 chunks
        int row = c / 48, cho = c - row * 48;
        int j = cho >> 4, kc = (cho & 15) * 16;
        int bb = (rbase + row) & 255;
        int src = (t >= 2) ? (t - 2 + j) : ((j <= t) ? j : -1);  // j-th OLDEST tap
        v4i v = (v4i){0, 0, 0, 0};
        if (src >= 0) v = *(const v4i*)(s3 + ((size_t)(src * 256 + bb)) * 256 + kc);
        *(v4i*)(As + row * 784 + cho * 16) = v;
    }
    __syncthreads();
    const int nb = wave * 64;
    const double scl[5] = { 0x1p-38, 0x1p-30, 0x1p-22, 0x1p-14, 0x1p-6 };
    const double s = scl[d];
    const signed char* Bp = Bdtc + (size_t)d * 196608 + (size_t)(nb + col) * 768 + quad * 16;
    v4i acc[4][2];
#pragma unroll
    for (int nt = 0; nt < 4; ++nt) { acc[nt][0] = (v4i){0,0,0,0}; acc[nt][1] = (v4i){0,0,0,0}; }
    v4i Bc[4], Bn[4];
#pragma unroll
    for (int nt = 0; nt < 4; ++nt) Bc[nt] = *(const v4i*)(Bp + nt * 12288);
#pragma unroll
    for (int kk = 0; kk < 12; ++kk) {
        if (kk < 11) {
#pragma unroll
            for (int nt = 0; nt < 4; ++nt)
                Bn[nt] = *(const v4i*)(Bp + nt * 12288 + (kk + 1) * 64);
        }
        v4i Af0 = *(const v4i*)(As + (lane & 15) * 784 + kk * 64 + quad * 16);
        v4i Af1 = *(const v4i*)(As + ((lane & 15) + 16) * 784 + kk * 64 + quad * 16);
#pragma unroll
        for (int nt = 0; nt < 4; ++nt) {
            acc[nt][0] = __builtin_amdgcn_mfma_i32_16x16x64_i8(Af0, Bc[nt], acc[nt][0], 0, 0, 0);
            acc[nt][1] = __builtin_amdgcn_mfma_i32_16x16x64_i8(Af1, Bc[nt], acc[nt][1], 0, 0, 0);
        }
#pragma unroll
        for (int nt = 0; nt < 4; ++nt) Bc[nt] = Bn[nt];
    }
#pragma unroll
    for (int nt = 0; nt < 4; ++nt)
#pragma unroll
        for (int mi = 0; mi < 2; ++mi)
#pragma unroll
            for (int r = 0; r < 4; ++r) {
                int row = rbase + mi * 16 + quad * 4 + r;
                atomicAdd(&psp[(size_t)row * 256 + nb + nt * 16 + col],
                          (double)acc[nt][mi][r] * s);
            }
}

// ---------------- sequential LIF sweep over [T][B*256] fp64 psp -> spikes -------
__global__ __launch_bounds__(256) void k_lif_flat(const double* __restrict__ psp,
        unsigned char* __restrict__ out) {
    int n = blockIdx.x * 256 + threadIdx.x;
    double cur = 0.0, vlt = 0.0;
    int spk = 0;
    for (int t = 0; t < T; ++t) {
        double z = psp[(size_t)t * 65536 + n];
        cur = 0.5 * cur + z;
        vlt = (spk ? 0.0 : 0.75 * vlt) + cur;
        spk = (vlt > 0.5) ? 1 : 0;
        out[(size_t)t * 65536 + n] = (unsigned char)spk;
    }
}

// ---------------- recurrent layer: dense fp64 matvec, weights in registers ------
__global__ __launch_bounds__(1024) void k_rec(const unsigned char* __restrict__ tcspk,
        const double* __restrict__ recwt, const float* __restrict__ rb,
        unsigned char* __restrict__ rspk) {
    __shared__ double rs[256];
    __shared__ double partial[4][256];
    int b  = blockIdx.x;
    int oc = threadIdx.x & 255;
    int ks = threadIdx.x >> 8;              // 0..3
    double wreg[64];
#pragma unroll
    for (int i = 0; i < 64; ++i)
        wreg[i] = recwt[(size_t)(ks * 64 + i) * 256 + oc];
    if (ks == 0) rs[oc] = 0.0;
    double bias = (double)rb[oc];
    double cur = 0.0, vlt = 0.0;
    int spk = 0;
    __syncthreads();
    for (int t = 0; t < T; ++t) {
        const double* rsk = &rs[ks * 64];
        double z0 = 0.0, z1 = 0.0;
#pragma unroll
        for (int i = 0; i < 64; i += 2) {
            z0 = fma(wreg[i],     rsk[i],     z0);
            z1 = fma(wreg[i + 1], rsk[i + 1], z1);
        }
        partial[ks][oc] = z0 + z1;
        __syncthreads();
        if (ks == 0) {
            double z = bias + (double)tcspk[((size_t)t * B + b) * 256 + oc]
                     + ((partial[0][oc] + partial[1][oc]) + (partial[2][oc] + partial[3][oc]));
            cur = 0.5 * cur + z;
            vlt = (spk ? 0.0 : 0.75 * vlt) + cur;
            spk = (vlt > 0.5) ? 1 : 0;
            rspk[((size_t)t * B + b) * 256 + oc] = (unsigned char)spk;
            rs[oc] = (double)spk;
        }
        __syncthreads();
    }
}

// ---------------- fc1 PSP: exact i8-digit GEMM, N=128 K=256 ----------------
__global__ __launch_bounds__(256) void k_f1psp(const unsigned char* __restrict__ rspk,
        const signed char* __restrict__ Bdf1, const float* __restrict__ f1b,
        double* __restrict__ psp) {
    __shared__ __align__(16) unsigned char As[16 * 272];
    const int mt = blockIdx.x, rbase = mt * 16;
    const int tid = threadIdx.x;
    const int wave = tid >> 6, lane = tid & 63;
    const int col = lane & 15, quad = lane >> 4;
    if (tid < 256) {                               // 16 rows x 16 chunks
        int row = tid >> 4, cho = tid & 15;
        v4i v = *(const v4i*)(rspk + (size_t)(rbase + row) * 256 + cho * 16);
        *(v4i*)(As + row * 272 + cho * 16) = v;
    }
    __syncthreads();
    const int nb = wave * 32;
    const double scl[5] = { 0x1p-38, 0x1p-30, 0x1p-22, 0x1p-14, 0x1p-6 };
    double psum[2][4];
#pragma unroll
    for (int nt = 0; nt < 2; ++nt)
#pragma unroll
        for (int r = 0; r < 4; ++r) psum[nt][r] = 0.0;
    for (int d = 0; d < 5; ++d) {
        v4i acc[2];
        acc[0] = (v4i){0, 0, 0, 0};
        acc[1] = (v4i){0, 0, 0, 0};
#pragma unroll
        for (int kk = 0; kk < 4; ++kk) {
            v4i Af = *(const v4i*)(As + (lane & 15) * 272 + kk * 64 + quad * 16);
#pragma unroll
            for (int nt = 0; nt < 2; ++nt) {
                v4i Bf = *(const v4i*)(Bdf1 + (size_t)d * 32768
                        + (size_t)(nb + nt * 16 + col) * 256 + kk * 64 + quad * 16);
                acc[nt] = __builtin_amdgcn_mfma_i32_16x16x64_i8(Af, Bf, acc[nt], 0, 0, 0);
            }
        }
        double s = scl[d];
#pragma unroll
        for (int nt = 0; nt < 2; ++nt)
#pragma unroll
            for (int r = 0; r < 4; ++r)
                psum[nt][r] = fma((double)acc[nt][r], s, psum[nt][r]);
    }
#pragma unroll
    for (int nt = 0; nt < 2; ++nt) {
        int n = nb + nt * 16 + col;
        double bias = (double)f1b[n];
#pragma unroll
        for (int r = 0; r < 4; ++r) {
            int row = rbase + quad * 4 + r;
            psp[(size_t)row * 128 + n] = bias + psum[nt][r];
        }
    }
}

// ---------------- fc1 LIF (registers) + fc2 via end-of-time reduction ----------
__global__ __launch_bounds__(128) void k_fc_out(const double* __restrict__ psp,
        const float* __restrict__ fc2w, const float* __restrict__ tsw,
        float* __restrict__ out) {
    __shared__ double sm[128];
    int b = blockIdx.x, oc = threadIdx.x;
    double ps[T];
#pragma unroll
    for (int t = 0; t < T; ++t)
        ps[t] = psp[((size_t)t * B + b) * 128 + oc];
    double cur = 0.0, vlt = 0.0, sAcc = 0.0;
    int spk = 0;
#pragma unroll
    for (int t = 0; t < T; ++t) {
        cur = 0.5 * cur + ps[t];
        vlt = (spk ? 0.0 : 0.75 * vlt) + cur;
        spk = (vlt > 0.5) ? 1 : 0;
        if (spk) sAcc += (double)tsw[t];
    }
    sm[oc] = sAcc;
    __syncthreads();
    if (oc < 2) {
        double s = 0.0;
        for (int k = 0; k < 128; ++k)
            s = fma(sm[k], (double)fc2w[oc * 128 + k], s);
        out[b * 2 + oc] = (float)s;
    }
}

extern "C" void kernel_launch(void* const* d_in, const int* in_sizes, int n_in,
                              void* d_out, int out_size, void* d_ws, size_t ws_size,
                              hipStream_t stream) {
    const float* x   = (const float*)d_in[0];
    const float* c1w = (const float*)d_in[1];
    const float* c1b = (const float*)d_in[2];
    const float* c2w = (const float*)d_in[3];
    const float* c2b = (const float*)d_in[4];
    const float* c3w = (const float*)d_in[5];
    const float* c3b = (const float*)d_in[6];
    const float* tcw = (const float*)d_in[7];
    const float* tcb = (const float*)d_in[8];
    const float* rcw = (const float*)d_in[9];
    const float* rcb = (const float*)d_in[10];
    const float* f1w = (const float*)d_in[11];
    const float* f1b = (const float*)d_in[12];
    const float* f2w = (const float*)d_in[13];
    const float* tsw = (const float*)d_in[14];

    char* ws = (char*)d_ws;
    signed char* Bd2      = (signed char*)(ws + OFF_BD2);
    signed char* Bd3      = (signed char*)(ws + OFF_BD3);
    signed char* Bdtc     = (signed char*)(ws + OFF_BDTC);
    signed char* Bdf1     = (signed char*)(ws + OFF_BDF1);
    double* recwt         = (double*)(ws + OFF_RECWT);
    unsigned char* s1     = (unsigned char*)(ws + OFF_S1);
    unsigned char* pool   = (unsigned char*)(ws + OFF_POOL);
    double* psp3          = (double*)(ws + OFF_PSP3);
    unsigned char* s3     = (unsigned char*)(ws + OFF_S3);
    double* psptc         = (double*)(ws + OFF_PSPTC);
    unsigned char* tcs    = (unsigned char*)(ws + OFF_TC);
    unsigned char* rsp    = (unsigned char*)(ws + OFF_R);
    double* pspf1         = (double*)(ws + OFF_PSPF1);

    k_prep    <<<256,  256, 0, stream>>>(rcw, recwt);
    k_prepd   <<<2336, 256, 0, stream>>>(c2w, c3w, tcw, f1w, Bd2, Bd3, Bdtc, Bdf1);
    k_fill3   <<<8192, 256, 0, stream>>>(c3b, psp3);
    k_filltc  <<<8192, 256, 0, stream>>>(tcb, psptc);
    k_conv1   <<<256,  256, 0, stream>>>(x, c1w, c1b, s1);
    k_conv2   <<<2304, 256, 0, stream>>>(s1, Bd2, c2b, pool);
    k_c3psp   <<<1280, 256, 0, stream>>>(pool, Bd3, psp3);
    k_lif_flat<<<256,  256, 0, stream>>>(psp3, s3);
    k_tcpsp   <<<1280, 256, 0, stream>>>(s3, Bdtc, psptc);
    k_lif_flat<<<256,  256, 0, stream>>>(psptc, tcs);
    k_rec     <<<256, 1024, 0, stream>>>(tcs, recwt, rcb, rsp);
    k_f1psp   <<<512,  256, 0, stream>>>(rsp, Bdf1, f1b, pspf1);
    k_fc_out  <<<256,  128, 0, stream>>>(pspf1, f2w, tsw, (float*)d_out);
}

// Round 7
// 608.145 us; speedup vs baseline: 1.1861x; 1.1861x over previous
//
#include <hip/hip_runtime.h>

#define T 32
#define B 256

typedef int v4i __attribute__((ext_vector_type(4)));

// ---------------- workspace byte offsets ----------------
#define OFF_BD2   0            // int8 [5][128][576]   conv2 digits      368,640
#define OFF_BD3   368640       // int8 [5][256][1152]  conv3 digits    1,474,560
#define OFF_BDTC  1843200      // int8 [5][256][768]   tc digits         983,040
#define OFF_BDF1  2826240      // int8 [5][128][256]   fc1 digits        163,840
#define OFF_RECWT 2990080      // double [256][256]                      524,288
#define OFF_S1    3514368      // uchar [T][B][pix64][ic64]           33,554,432
#define OFF_POOL  37068800     // uchar [w9][t32][b256][oc128]         9,437,184
#define OFF_PSP3  46505984     // double [8192][256]                  16,777,216
#define OFF_S3    63283200     // uchar [t][b][256]                    2,097,152
#define OFF_PSPTC 65380352     // double [8192][256]                  16,777,216
#define OFF_TC    82157568     // uchar [t][b][256]                    2,097,152
#define OFF_R     84254720     // uchar [t][b][256]                    2,097,152
#define OFF_PSPF1 OFF_PSPTC    // double [8192][128] — reuses psptc (retired)
// total 86,351,872 bytes

// ---------------- weight digit decomposition + rec fp64 transpose ----------------
// W = rint(w*2^38), 5 signed base-256 digits; layouts: Bd[d][oc][k]
__global__ __launch_bounds__(256) void k_prepd(const float* __restrict__ c2w,
        const float* __restrict__ c3w, const float* __restrict__ tcw,
        const float* __restrict__ f1w, const float* __restrict__ rcw,
        signed char* __restrict__ Bd2, signed char* __restrict__ Bd3,
        signed char* __restrict__ Bdtc, signed char* __restrict__ Bdf1,
        double* __restrict__ recwt) {
    int idx = blockIdx.x * 256 + threadIdx.x;
    float w; signed char* base; int plane, off;
    if (idx < 73728) {                       // conv2: k=(ky*3+kx)*64+ic
        int oc = idx / 576, kpos = idx - oc * 576;
        int kk = kpos >> 6, ic = kpos & 63;
        int ky = kk / 3, kx = kk - ky * 3;
        w = c2w[((oc * 64 + ic) * 3 + ky) * 3 + kx];
        base = Bd2; plane = 73728; off = idx;
    } else if (idx < 368640) {               // conv3: k = win*128+ic
        int m = idx - 73728;
        int oc = m / 1152, kpos = m - oc * 1152;
        int win = kpos >> 7, ic = kpos & 127;
        w = c3w[(oc * 128 + ic) * 9 + win];
        base = Bd3; plane = 294912; off = m;
    } else if (idx < 565248) {               // tc: k = j*256+kc (j = oldest-first tap)
        int m = idx - 368640;
        int oc = m / 768, kpos = m - oc * 768;
        int j = kpos >> 8, kc = kpos & 255;
        w = tcw[(j * 256 + oc) * 256 + kc];
        base = Bdtc; plane = 196608; off = m;
    } else if (idx < 598016) {               // fc1: k = kc
        int m = idx - 565248;
        int oc = m >> 8, kc = m & 255;
        w = f1w[oc * 256 + kc];
        base = Bdf1; plane = 32768; off = m;
    } else if (idx < 663552) {               // recwt[k][oc] <- rec_w[oc][k]
        int m = idx - 598016;
        int oc = m & 255, k = m >> 8;
        recwt[m] = (double)rcw[oc * 256 + k];
        return;
    } else return;
    long long W = (long long)rint((double)w * 274877906944.0);   // 2^38
#pragma unroll
    for (int d = 0; d < 4; ++d) {
        int dig = (int)(((W + 128) & 255) - 128);
        base[d * plane + off] = (signed char)dig;
        W = (W - dig) >> 8;
    }
    base[4 * plane + off] = (signed char)W;
}

// ---------------- conv1 + LIF1 -> s1 [t][b][pix][ic], fp64 state ----------------
// grid 1024 = B x 4 px-quarters ; block 256 = 64 oc x 4 sub ; thread owns 4 px
__global__ __launch_bounds__(256) void k_conv1(const float* __restrict__ x,
        const float* __restrict__ w1, const float* __restrict__ b1,
        unsigned char* __restrict__ s1) {
    __shared__ float xl[3200];
    int b  = blockIdx.x >> 2;
    int bp = blockIdx.x & 3;
    int oc = threadIdx.x & 63;
    int sub = threadIdx.x >> 6;             // 0..3
    const float* xb = x + b * 3200;         // input_data[b][0][10][10][T], t innermost
    for (int i = threadIdx.x; i < 3200; i += 256)
        xl[(i & 31) * 100 + (i >> 5)] = xb[i];   // LDS [t][pos]
    double wd[9];
#pragma unroll
    for (int j = 0; j < 9; ++j) wd[j] = (double)w1[oc * 9 + j];
    double bias = (double)b1[oc];
    __syncthreads();
    double cur[4], vlt[4];
    unsigned spkb = 0;
#pragma unroll
    for (int i = 0; i < 4; ++i) { cur[i] = 0.0; vlt[i] = 0.0; }
    const int pixbase = bp * 16 + sub * 4;
    for (int t = 0; t < T; ++t) {
#pragma unroll
        for (int i = 0; i < 4; ++i) {
            int pix = pixbase + i;
            int oy = pix >> 3, ox = pix & 7;
            const float* xt = &xl[t * 100 + oy * 10 + ox];
            double z = bias;
#pragma unroll
            for (int ky = 0; ky < 3; ++ky)
#pragma unroll
                for (int kx = 0; kx < 3; ++kx)
                    z = fma(wd[ky * 3 + kx], (double)xt[ky * 10 + kx], z);
            cur[i] = 0.5 * cur[i] + z;
            int s = (spkb >> i) & 1;
            vlt[i] = (s ? 0.0 : 0.75 * vlt[i]) + cur[i];
            s = (vlt[i] > 0.5) ? 1 : 0;
            spkb = (spkb & ~(1u << i)) | ((unsigned)s << i);
            s1[((size_t)(t * B + b) * 64 + pix) * 64 + oc] = (unsigned char)s;
        }
    }
}

// ---------------- conv2: barrier-free i8-digit MFMA with in-register LIF --------
// grid B*9 ; block 256 (4 waves). M-row m = px*4 + tq  =>  C/D lane (col,quad)
// holds ONE neuron (oc=col, px=quad) with 4 consecutive t per tile: LIF runs
// entirely in registers. No pl roundtrip, no barriers in the K/M loop.
__global__ __launch_bounds__(256) void k_conv2(const unsigned char* __restrict__ s1,
        const signed char* __restrict__ Bd2, const float* __restrict__ cb2,
        unsigned char* __restrict__ pooled) {
    __shared__ __align__(16) unsigned char As[32 * 1024];   // [t][swz(p,qo)][16]
    __shared__ unsigned smask[4][64];
    const int b = blockIdx.x / 9;
    const int w = blockIdx.x - b * 9;
    const int wy = w / 3, wx = w - wy * 3;
    const int tid = threadIdx.x;
    const int wave = tid >> 6, lane = tid & 63;
    const int col = lane & 15, quad = lane >> 4;
    const int m = lane & 15;
    const int px = m >> 2, tq = m & 3;          // A-row: px major, t minor
    const int py0 = px >> 1, px0 = px & 1;
    const double scl[5] = { 0x1p-38, 0x1p-30, 0x1p-22, 0x1p-14, 0x1p-6 };

    {   // stage A: p varies fastest across lanes (2-way-free write phases)
        const int pixbase = (2 * wy) * 8 + 2 * wx;
        for (int c = tid; c < 2048; c += 256) {
            int t = c >> 6, rem = c & 63;
            int p = rem & 15, qo = rem >> 4;
            int ly = p >> 2, lx = p & 3;
            int pix = pixbase + ly * 8 + lx;
            v4i v = *(const v4i*)(s1 + (((size_t)(t * B + b) * 64 + pix) << 6) + qo * 16);
            *(v4i*)(As + t * 1024 + ((qo * 16) + (p ^ (2 * (t & 3)))) * 16) = v;
        }
    }
    __syncthreads();

    for (int nh = 0; nh < 2; ++nh) {
        const int oc = nh * 64 + wave * 16 + col;
        const signed char* Bw = Bd2 + (size_t)oc * 576 + quad * 16;
        double cur = 0.0, vlt = 0.0;
        int spk = 0;
        unsigned bits = 0;
        double bias = (double)cb2[oc];

        for (int mp = 0; mp < 4; ++mp) {
            const int t0 = mp * 8 + tq;          // j=0 timestep for this lane's A-row
            const int t1 = t0 + 4;               // j=1
            const int sw0 = 2 * tq;              // swizzle key (t&3 == tq)
            v4i acc[5][2];
#pragma unroll
            for (int d = 0; d < 5; ++d) {
                acc[d][0] = (v4i){0, 0, 0, 0};
                acc[d][1] = (v4i){0, 0, 0, 0};
            }
            v4i Bc[5], Bn[5];
#pragma unroll
            for (int d = 0; d < 5; ++d) Bc[d] = *(const v4i*)(Bw + d * 73728);
#pragma unroll
            for (int kk = 0; kk < 9; ++kk) {
                if (kk < 8) {
#pragma unroll
                    for (int d = 0; d < 5; ++d)
                        Bn[d] = *(const v4i*)(Bw + d * 73728 + (kk + 1) * 64);
                }
                const int ky = kk / 3, kx = kk - ky * 3;
                const int p = (py0 + ky) * 4 + (px0 + kx);
                const int f = (quad * 16 + (p ^ sw0)) * 16;
                v4i Af0 = *(const v4i*)(As + t0 * 1024 + f);
                v4i Af1 = *(const v4i*)(As + t1 * 1024 + f);
#pragma unroll
                for (int d = 0; d < 5; ++d) {
                    acc[d][0] = __builtin_amdgcn_mfma_i32_16x16x64_i8(Af0, Bc[d], acc[d][0], 0, 0, 0);
                    acc[d][1] = __builtin_amdgcn_mfma_i32_16x16x64_i8(Af1, Bc[d], acc[d][1], 0, 0, 0);
                }
#pragma unroll
                for (int d = 0; d < 5; ++d) Bc[d] = Bn[d];
            }
            // in-register LIF: lane owns (oc, px=quad); acc row r -> t = mp*8+j*4+r
#pragma unroll
            for (int j = 0; j < 2; ++j)
#pragma unroll
                for (int r = 0; r < 4; ++r) {
                    double p = 0.0;
#pragma unroll
                    for (int d = 0; d < 5; ++d)
                        p = fma((double)acc[d][j][r], scl[d], p);
                    int t = mp * 8 + j * 4 + r;
                    cur = 0.5 * cur + (bias + p);
                    vlt = (spk ? 0.0 : 0.75 * vlt) + cur;
                    spk = (vlt > 0.5) ? 1 : 0;
                    bits |= ((unsigned)spk) << t;
                }
        }
        smask[quad][wave * 16 + col] = bits;
        __syncthreads();
        {   // avgpool: lane (quad,col) handles t = quad*8..quad*8+7 for its oc
            unsigned m0 = smask[0][wave * 16 + col], m1 = smask[1][wave * 16 + col];
            unsigned m2 = smask[2][wave * 16 + col], m3 = smask[3][wave * 16 + col];
#pragma unroll
            for (int q = 0; q < 8; ++q) {
                int t = quad * 8 + q;
                unsigned s = ((m0 >> t) & 1) + ((m1 >> t) & 1) + ((m2 >> t) & 1) + ((m3 >> t) & 1);
                pooled[(size_t)((w * 32 + t) * 256 + b) * 128 + oc] = (unsigned char)s;
            }
        }
        __syncthreads();
    }
}

// ---------------- conv3 PSP: exact i8-digit GEMM, M=8192 N=256 K=1152 ----------
// grid 512 (M16 tiles) ; block 256 (4 waves x N64) ; direct store + bias
__global__ __launch_bounds__(256) void k_c3psp(const unsigned char* __restrict__ pooled,
        const signed char* __restrict__ Bd3, const float* __restrict__ b3,
        double* __restrict__ psp) {
    __shared__ __align__(16) unsigned char As[16 * 1168];   // row pad 16
    const int mt = blockIdx.x, rbase = mt * 16;
    const int tid = threadIdx.x;
    const int wave = tid >> 6, lane = tid & 63;
    const int col = lane & 15, quad = lane >> 4;
    for (int c = tid; c < 1152; c += 256) {       // 16 rows x 72 chunks
        int row = c / 72, cho = c - row * 72;
        int wn = cho >> 3, ico = (cho & 7) * 16;
        v4i v = *(const v4i*)(pooled + ((size_t)(wn * 8192) + rbase + row) * 128 + ico);
        *(v4i*)(As + row * 1168 + cho * 16) = v;
    }
    __syncthreads();
    const int nb = wave * 64;
    const double scl[5] = { 0x1p-40, 0x1p-32, 0x1p-24, 0x1p-16, 0x1p-8 };  // folds /4 pool
    double psum[4][4];
#pragma unroll
    for (int nt = 0; nt < 4; ++nt)
#pragma unroll
        for (int r = 0; r < 4; ++r) psum[nt][r] = 0.0;
    for (int d = 0; d < 5; ++d) {
        const signed char* Bp = Bd3 + (size_t)d * 294912 + (size_t)(nb + col) * 1152 + quad * 16;
        v4i acc[4];
#pragma unroll
        for (int nt = 0; nt < 4; ++nt) acc[nt] = (v4i){0, 0, 0, 0};
        v4i Bc[4], Bn[4];
#pragma unroll
        for (int nt = 0; nt < 4; ++nt) Bc[nt] = *(const v4i*)(Bp + nt * 18432);
#pragma unroll
        for (int kk = 0; kk < 18; ++kk) {
            if (kk < 17) {
#pragma unroll
                for (int nt = 0; nt < 4; ++nt)
                    Bn[nt] = *(const v4i*)(Bp + nt * 18432 + (kk + 1) * 64);
            }
            v4i Af = *(const v4i*)(As + (lane & 15) * 1168 + kk * 64 + quad * 16);
#pragma unroll
            for (int nt = 0; nt < 4; ++nt)
                acc[nt] = __builtin_amdgcn_mfma_i32_16x16x64_i8(Af, Bc[nt], acc[nt], 0, 0, 0);
#pragma unroll
            for (int nt = 0; nt < 4; ++nt) Bc[nt] = Bn[nt];
        }
        double s = scl[d];
#pragma unroll
        for (int nt = 0; nt < 4; ++nt)
#pragma unroll
            for (int r = 0; r < 4; ++r)
                psum[nt][r] = fma((double)acc[nt][r], s, psum[nt][r]);
    }
#pragma unroll
    for (int nt = 0; nt < 4; ++nt) {
        double bias = (double)b3[nb + nt * 16 + col];
#pragma unroll
        for (int r = 0; r < 4; ++r) {
            int row = rbase + quad * 4 + r;
            psp[(size_t)row * 256 + nb + nt * 16 + col] = bias + psum[nt][r];
        }
    }
}

// ---------------- tc PSP: exact i8-digit GEMM, K=768 (3-tap history) ------------
__global__ __launch_bounds__(256) void k_tcpsp(const unsigned char* __restrict__ s3,
        const signed char* __restrict__ Bdtc, const float* __restrict__ tcb,
        double* __restrict__ psp) {
    __shared__ __align__(16) unsigned char As[16 * 784];
    const int mt = blockIdx.x, rbase = mt * 16;
    const int t = rbase >> 8;                      // constant per block
    const int tid = threadIdx.x;
    const int wave = tid >> 6, lane = tid & 63;
    const int col = lane & 15, quad = lane >> 4;
    for (int c = tid; c < 768; c += 256) {         // 16 rows x 48 chunks
        int row = c / 48, cho = c - row * 48;
        int j = cho >> 4, kc = (cho & 15) * 16;
        int bb = (rbase + row) & 255;
        int src = (t >= 2) ? (t - 2 + j) : ((j <= t) ? j : -1);  // j-th OLDEST tap
        v4i v = (v4i){0, 0, 0, 0};
        if (src >= 0) v = *(const v4i*)(s3 + ((size_t)(src * 256 + bb)) * 256 + kc);
        *(v4i*)(As + row * 784 + cho * 16) = v;
    }
    __syncthreads();
    const int nb = wave * 64;
    const double scl[5] = { 0x1p-38, 0x1p-30, 0x1p-22, 0x1p-14, 0x1p-6 };
    double psum[4][4];
#pragma unroll
    for (int nt = 0; nt < 4; ++nt)
#pragma unroll
        for (int r = 0; r < 4; ++r) psum[nt][r] = 0.0;
    for (int d = 0; d < 5; ++d) {
        const signed char* Bp = Bdtc + (size_t)d * 196608 + (size_t)(nb + col) * 768 + quad * 16;
        v4i acc[4];
#pragma unroll
        for (int nt = 0; nt < 4; ++nt) acc[nt] = (v4i){0, 0, 0, 0};
        v4i Bc[4], Bn[4];
#pragma unroll
        for (int nt = 0; nt < 4; ++nt) Bc[nt] = *(const v4i*)(Bp + nt * 12288);
#pragma unroll
        for (int kk = 0; kk < 12; ++kk) {
            if (kk < 11) {
#pragma unroll
                for (int nt = 0; nt < 4; ++nt)
                    Bn[nt] = *(const v4i*)(Bp + nt * 12288 + (kk + 1) * 64);
            }
            v4i Af = *(const v4i*)(As + (lane & 15) * 784 + kk * 64 + quad * 16);
#pragma unroll
            for (int nt = 0; nt < 4; ++nt)
                acc[nt] = __builtin_amdgcn_mfma_i32_16x16x64_i8(Af, Bc[nt], acc[nt], 0, 0, 0);
#pragma unroll
            for (int nt = 0; nt < 4; ++nt) Bc[nt] = Bn[nt];
        }
        double s = scl[d];
#pragma unroll
        for (int nt = 0; nt < 4; ++nt)
#pragma unroll
            for (int r = 0; r < 4; ++r)
                psum[nt][r] = fma((double)acc[nt][r], s, psum[nt][r]);
    }
#pragma unroll
    for (int nt = 0; nt < 4; ++nt) {
        int n = nb + nt * 16 + col;
        double bias = (double)tcb[n];
        if (t >= 1) bias += (double)tcb[256 + n];
        if (t >= 2) bias += (double)tcb[512 + n];
#pragma unroll
        for (int r = 0; r < 4; ++r) {
            int row = rbase + quad * 4 + r;
            psp[(size_t)row * 256 + n] = bias + psum[nt][r];
        }
    }
}

// ---------------- sequential LIF sweep over [T][B*256] fp64 psp -> spikes -------
__global__ __launch_bounds__(256) void k_lif_flat(const double* __restrict__ psp,
        unsigned char* __restrict__ out) {
    int n = blockIdx.x * 256 + threadIdx.x;
    double cur = 0.0, vlt = 0.0;
    int spk = 0;
    for (int t = 0; t < T; ++t) {
        double z = psp[(size_t)t * 65536 + n];
        cur = 0.5 * cur + z;
        vlt = (spk ? 0.0 : 0.75 * vlt) + cur;
        spk = (vlt > 0.5) ? 1 : 0;
        out[(size_t)t * 65536 + n] = (unsigned char)spk;
    }
}

// ---------------- recurrent layer: dense fp64 matvec, weights in registers ------
__global__ __launch_bounds__(1024) void k_rec(const unsigned char* __restrict__ tcspk,
        const double* __restrict__ recwt, const float* __restrict__ rb,
        unsigned char* __restrict__ rspk) {
    __shared__ double rs[256];
    __shared__ double partial[4][256];
    int b  = blockIdx.x;
    int oc = threadIdx.x & 255;
    int ks = threadIdx.x >> 8;              // 0..3
    double wreg[64];
#pragma unroll
    for (int i = 0; i < 64; ++i)
        wreg[i] = recwt[(size_t)(ks * 64 + i) * 256 + oc];
    if (ks == 0) rs[oc] = 0.0;
    double bias = (double)rb[oc];
    double cur = 0.0, vlt = 0.0;
    int spk = 0;
    __syncthreads();
    for (int t = 0; t < T; ++t) {
        const double* rsk = &rs[ks * 64];
        double z0 = 0.0, z1 = 0.0;
#pragma unroll
        for (int i = 0; i < 64; i += 2) {
            z0 = fma(wreg[i],     rsk[i],     z0);
            z1 = fma(wreg[i + 1], rsk[i + 1], z1);
        }
        partial[ks][oc] = z0 + z1;
        __syncthreads();
        if (ks == 0) {
            double z = bias + (double)tcspk[((size_t)t * B + b) * 256 + oc]
                     + ((partial[0][oc] + partial[1][oc]) + (partial[2][oc] + partial[3][oc]));
            cur = 0.5 * cur + z;
            vlt = (spk ? 0.0 : 0.75 * vlt) + cur;
            spk = (vlt > 0.5) ? 1 : 0;
            rspk[((size_t)t * B + b) * 256 + oc] = (unsigned char)spk;
            rs[oc] = (double)spk;
        }
        __syncthreads();
    }
}

// ---------------- fc1 PSP: exact i8-digit GEMM, N=128 K=256 ----------------
__global__ __launch_bounds__(256) void k_f1psp(const unsigned char* __restrict__ rspk,
        const signed char* __restrict__ Bdf1, const float* __restrict__ f1b,
        double* __restrict__ psp) {
    __shared__ __align__(16) unsigned char As[16 * 272];
    const int mt = blockIdx.x, rbase = mt * 16;
    const int tid = threadIdx.x;
    const int wave = tid >> 6, lane = tid & 63;
    const int col = lane & 15, quad = lane >> 4;
    if (tid < 256) {                               // 16 rows x 16 chunks
        int row = tid >> 4, cho = tid & 15;
        v4i v = *(const v4i*)(rspk + (size_t)(rbase + row) * 256 + cho * 16);
        *(v4i*)(As + row * 272 + cho * 16) = v;
    }
    __syncthreads();
    const int nb = wave * 32;
    const double scl[5] = { 0x1p-38, 0x1p-30, 0x1p-22, 0x1p-14, 0x1p-6 };
    double psum[2][4];
#pragma unroll
    for (int nt = 0; nt < 2; ++nt)
#pragma unroll
        for (int r = 0; r < 4; ++r) psum[nt][r] = 0.0;
    for (int d = 0; d < 5; ++d) {
        v4i acc[2];
        acc[0] = (v4i){0, 0, 0, 0};
        acc[1] = (v4i){0, 0, 0, 0};
#pragma unroll
        for (int kk = 0; kk < 4; ++kk) {
            v4i Af = *(const v4i*)(As + (lane & 15) * 272 + kk * 64 + quad * 16);
#pragma unroll
            for (int nt = 0; nt < 2; ++nt) {
                v4i Bf = *(const v4i*)(Bdf1 + (size_t)d * 32768
                        + (size_t)(nb + nt * 16 + col) * 256 + kk * 64 + quad * 16);
                acc[nt] = __builtin_amdgcn_mfma_i32_16x16x64_i8(Af, Bf, acc[nt], 0, 0, 0);
            }
        }
        double s = scl[d];
#pragma unroll
        for (int nt = 0; nt < 2; ++nt)
#pragma unroll
            for (int r = 0; r < 4; ++r)
                psum[nt][r] = fma((double)acc[nt][r], s, psum[nt][r]);
    }
#pragma unroll
    for (int nt = 0; nt < 2; ++nt) {
        int n = nb + nt * 16 + col;
        double bias = (double)f1b[n];
#pragma unroll
        for (int r = 0; r < 4; ++r) {
            int row = rbase + quad * 4 + r;
            psp[(size_t)row * 128 + n] = bias + psum[nt][r];
        }
    }
}

// ---------------- fc1 LIF (registers) + fc2 via end-of-time reduction ----------
__global__ __launch_bounds__(128) void k_fc_out(const double* __restrict__ psp,
        const float* __restrict__ fc2w, const float* __restrict__ tsw,
        float* __restrict__ out) {
    __shared__ double sm[128];
    int b = blockIdx.x, oc = threadIdx.x;
    double ps[T];
#pragma unroll
    for (int t = 0; t < T; ++t)
        ps[t] = psp[((size_t)t * B + b) * 128 + oc];
    double cur = 0.0, vlt = 0.0, sAcc = 0.0;
    int spk = 0;
#pragma unroll
    for (int t = 0; t < T; ++t) {
        cur = 0.5 * cur + ps[t];
        vlt = (spk ? 0.0 : 0.75 * vlt) + cur;
        spk = (vlt > 0.5) ? 1 : 0;
        if (spk) sAcc += (double)tsw[t];
    }
    sm[oc] = sAcc;
    __syncthreads();
    if (oc < 2) {
        double s = 0.0;
        for (int k = 0; k < 128; ++k)
            s = fma(sm[k], (double)fc2w[oc * 128 + k], s);
        out[b * 2 + oc] = (float)s;
    }
}

extern "C" void kernel_launch(void* const* d_in, const int* in_sizes, int n_in,
                              void* d_out, int out_size, void* d_ws, size_t ws_size,
                              hipStream_t stream) {
    const float* x   = (const float*)d_in[0];
    const float* c1w = (const float*)d_in[1];
    const float* c1b = (const float*)d_in[2];
    const float* c2w = (const float*)d_in[3];
    const float* c2b = (const float*)d_in[4];
    const float* c3w = (const float*)d_in[5];
    const float* c3b = (const float*)d_in[6];
    const float* tcw = (const float*)d_in[7];
    const float* tcb = (const float*)d_in[8];
    const float* rcw = (const float*)d_in[9];
    const float* rcb = (const float*)d_in[10];
    const float* f1w = (const float*)d_in[11];
    const float* f1b = (const float*)d_in[12];
    const float* f2w = (const float*)d_in[13];
    const float* tsw = (const float*)d_in[14];

    char* ws = (char*)d_ws;
    signed char* Bd2      = (signed char*)(ws + OFF_BD2);
    signed char* Bd3      = (signed char*)(ws + OFF_BD3);
    signed char* Bdtc     = (signed char*)(ws + OFF_BDTC);
    signed char* Bdf1     = (signed char*)(ws + OFF_BDF1);
    double* recwt         = (double*)(ws + OFF_RECWT);
    unsigned char* s1     = (unsigned char*)(ws + OFF_S1);
    unsigned char* pool   = (unsigned char*)(ws + OFF_POOL);
    double* psp3          = (double*)(ws + OFF_PSP3);
    unsigned char* s3     = (unsigned char*)(ws + OFF_S3);
    double* psptc         = (double*)(ws + OFF_PSPTC);
    unsigned char* tcs    = (unsigned char*)(ws + OFF_TC);
    unsigned char* rsp    = (unsigned char*)(ws + OFF_R);
    double* pspf1         = (double*)(ws + OFF_PSPF1);

    k_prepd   <<<2592, 256, 0, stream>>>(c2w, c3w, tcw, f1w, rcw, Bd2, Bd3, Bdtc, Bdf1, recwt);
    k_conv1   <<<1024, 256, 0, stream>>>(x, c1w, c1b, s1);
    k_conv2   <<<2304, 256, 0, stream>>>(s1, Bd2, c2b, pool);
    k_c3psp   <<<512,  256, 0, stream>>>(pool, Bd3, c3b, psp3);
    k_lif_flat<<<256,  256, 0, stream>>>(psp3, s3);
    k_tcpsp   <<<512,  256, 0, stream>>>(s3, Bdtc, tcb, psptc);
    k_lif_flat<<<256,  256, 0, stream>>>(psptc, tcs);
    k_rec     <<<256, 1024, 0, stream>>>(tcs, recwt, rcb, rsp);
    k_f1psp   <<<512,  256, 0, stream>>>(rsp, Bdf1, f1b, pspf1);
    k_fc_out  <<<256,  128, 0, stream>>>(pspf1, f2w, tsw, (float*)d_out);
}